// Round 6
// baseline (327.582 us; speedup 1.0000x reference)
//
#include <hip/hip_runtime.h>
#include <hip/hip_cooperative_groups.h>
#include <hip/hip_bf16.h>
#include <math.h>

// Problem dims (fixed by the reference): B=4096, M=2, D=2048
#define MROWS 8192   // B*M rows of the GEMM
#define KDIM  2048
#define NDIM  2048

#define BM 256
#define BN 256
#define BK 64
#define NT (KDIM / BK)   // 32 K-tiles

typedef short  v8s __attribute__((ext_vector_type(8)));   // 8 bf16 (4 VGPRs)
typedef float  v4f __attribute__((ext_vector_type(4)));   // MFMA acc

// workspace layout (bytes)
#define A_OFF   0ull
#define W_OFF   ((unsigned long long)MROWS * KDIM * 2ull)               // 32 MiB
#define MWZ_OFF (W_OFF + (unsigned long long)NDIM * KDIM * 2ull)        // +8 MiB

__device__ inline unsigned short f2bf(float f) {
    __hip_bfloat16 h = __float2bfloat16(f);   // RNE
    return *reinterpret_cast<unsigned short*>(&h);
}

#define SBAR()   __builtin_amdgcn_s_barrier()
#define LGKM0()  asm volatile("s_waitcnt lgkmcnt(0)" ::: "memory")
#define VMCNT(n) asm volatile("s_waitcnt vmcnt(" #n ")" ::: "memory")

template<int P>
__device__ __forceinline__ void mfma_phase(v4f (&acc)[8][4],
                                           const v8s (&b)[4][2],
                                           const v8s (&a)[2][2])
{
    __builtin_amdgcn_s_setprio(1);
    #pragma unroll
    for (int j = 0; j < 4; ++j) {
        acc[2*P  ][j] = __builtin_amdgcn_mfma_f32_16x16x32_bf16(b[j][0], a[0][0], acc[2*P  ][j], 0, 0, 0);
        acc[2*P+1][j] = __builtin_amdgcn_mfma_f32_16x16x32_bf16(b[j][0], a[1][0], acc[2*P+1][j], 0, 0, 0);
    }
    #pragma unroll
    for (int j = 0; j < 4; ++j) {
        acc[2*P  ][j] = __builtin_amdgcn_mfma_f32_16x16x32_bf16(b[j][1], a[0][1], acc[2*P  ][j], 0, 0, 0);
        acc[2*P+1][j] = __builtin_amdgcn_mfma_f32_16x16x32_bf16(b[j][1], a[1][1], acc[2*P+1][j], 0, 0, 0);
    }
    __builtin_amdgcn_s_setprio(0);
}

// ---------------------------------------------------------------------------
// FUSED kernel (cooperative): Section 1 converts A=bf16(x+emb[ids]) and
// W=bf16(Wt) + computes zeta, over the SAME 256-block grid as the gemm;
// grid-wide sync; Section 2 = the R3-measured-best gemm (75.7 us, MfmaUtil
// 36.5, SQ_LDS_BANK_CONFLICT 0, FETCH compulsory-only) byte-for-byte.
//
// Why fuse: across 6 benches, (total - gemm) is a constant ~120 +/- 6 us —
// larger than the gemm itself — and prep never appears in top-5 counters.
// Fusing (a) removes one launch + the inter-kernel serialization, (b) makes
// the single dispatch's rocprof duration cover everything, so
// total-vs-dispatch isolates harness overhead and dispatch-vs-76us isolates
// conversion cost for the next round's decision.
//
// R5 lesson folded in: B stays in LDS via global_load_lds (scattered per-lane
// register loads of B from L2 regressed 30%: L2 issue/latency bound).
//
// GEMM section (R3, verified): 256x256, 8 waves (2Mx4N), BK=64, static LDS
// dbuf (4 distinct objects so SIInsertWaitcnts can prove non-aliasing),
// 4-phase/K-tile with counted cross-barrier vmcnt, setprio on MFMA clusters,
// fetch-side XOR swizzle, same-tile quarter-interleaved staging (P3 stages
// quarters 0,2 while P3 reads rows in quarters 1,3 — disjoint; cross-wave
// safety from per-wave LGKM0 before each closing barrier).
// ---------------------------------------------------------------------------

// One K-tile = 4 phases. CA/CB: buffers computed from (and stage target for
// t+2, same parity). OA: other A buffer (stage target for t+1).
#define KTILE(CA, CB, OA, T)                                              \
  {                                                                       \
    v8s a[2][2], b[4][2];                                                 \
    b[0][0] = rdB(CB, 0, 0); b[0][1] = rdB(CB, 0, 1);                     \
    b[1][0] = rdB(CB, 1, 0); b[1][1] = rdB(CB, 1, 1);                     \
    b[2][0] = rdB(CB, 2, 0); b[2][1] = rdB(CB, 2, 1);                     \
    b[3][0] = rdB(CB, 3, 0); b[3][1] = rdB(CB, 3, 1);                     \
    a[0][0] = rdA(CA, 0, 0); a[0][1] = rdA(CA, 0, 1);                     \
    a[1][0] = rdA(CA, 1, 0); a[1][1] = rdA(CA, 1, 1);                     \
    stage(OA, gA, (T) + 1, 1); stage(OA, gA, (T) + 1, 3);                 \
    SBAR(); mfma_phase<0>(acc, b, a); LGKM0(); SBAR();                    \
    a[0][0] = rdA(CA, 2, 0); a[0][1] = rdA(CA, 2, 1);                     \
    a[1][0] = rdA(CA, 3, 0); a[1][1] = rdA(CA, 3, 1);                     \
    stage(CB, gB, (T) + 2, 0); stage(CB, gB, (T) + 2, 1);                 \
    SBAR(); mfma_phase<1>(acc, b, a); LGKM0(); VMCNT(10); SBAR();         \
    a[0][0] = rdA(CA, 4, 0); a[0][1] = rdA(CA, 4, 1);                     \
    a[1][0] = rdA(CA, 5, 0); a[1][1] = rdA(CA, 5, 1);                     \
    stage(CB, gB, (T) + 2, 2); stage(CB, gB, (T) + 2, 3);                 \
    SBAR(); mfma_phase<2>(acc, b, a); LGKM0(); SBAR();                    \
    a[0][0] = rdA(CA, 6, 0); a[0][1] = rdA(CA, 6, 1);                     \
    a[1][0] = rdA(CA, 7, 0); a[1][1] = rdA(CA, 7, 1);                     \
    stage(CA, gA, (T) + 2, 0); stage(CA, gA, (T) + 2, 2);                 \
    SBAR(); mfma_phase<3>(acc, b, a); LGKM0(); VMCNT(8); SBAR();          \
  }

__global__ __launch_bounds__(512, 2) void fused_kernel(
    const float* __restrict__ x, const int* __restrict__ ids,
    const float* __restrict__ mw, const float* __restrict__ emb,
    const float* __restrict__ Wrc, const float* __restrict__ brc,
    const float* __restrict__ Wt, const float* __restrict__ bt,
    unsigned short* __restrict__ Abf, unsigned short* __restrict__ Wbf,
    float* __restrict__ mwz, float* __restrict__ out)
{
    const int tid   = threadIdx.x;
    const int flatb = blockIdx.y * gridDim.x + blockIdx.x;   // 0..255

    // ===================== Section 1: conversion =====================
    if (flatb == 0) {
        __shared__ float red[512];
        float s = 0.f;
        for (int d = tid; d < KDIM; d += 512) s += Wrc[d];
        red[tid] = s;
        __syncthreads();
        for (int off = 256; off > 0; off >>= 1) {
            if (tid < off) red[tid] += red[tid + off];
            __syncthreads();
        }
        if (tid == 0) {
            float zeta = 1.0f / (1.0f + expf(-(0.2f * red[0] + brc[0])));
            mwz[0] = mw[0] * zeta;
            mwz[1] = mw[1] * zeta;
        }
    }

    // A conversion: 2,097,152 groups / 131,072 threads = 16 exact iters
    const int groupsA = MROWS * KDIM / 8;
    for (int g = flatb * 512 + tid; g < groupsA; g += 256 * 512) {
        const int row = g >> 8;            // 256 groups of 8 per 2048-row
        const int off = (g & 255) << 3;
        const int st  = ids[row];
        const float4* xp = (const float4*)(x   + (size_t)row * KDIM + off);
        const float4* ep = (const float4*)(emb + (size_t)st  * KDIM + off);
        float4 x0 = xp[0], x1 = xp[1];
        float4 e0 = ep[0], e1 = ep[1];
        v8s o;
        o[0] = (short)f2bf(x0.x + e0.x);
        o[1] = (short)f2bf(x0.y + e0.y);
        o[2] = (short)f2bf(x0.z + e0.z);
        o[3] = (short)f2bf(x0.w + e0.w);
        o[4] = (short)f2bf(x1.x + e1.x);
        o[5] = (short)f2bf(x1.y + e1.y);
        o[6] = (short)f2bf(x1.z + e1.z);
        o[7] = (short)f2bf(x1.w + e1.w);
        *(v8s*)(Abf + (size_t)g * 8) = o;
    }

    // W conversion: 524,288 groups / 131,072 threads = 4 exact iters
    const int groupsW = NDIM * KDIM / 8;
    for (int g = flatb * 512 + tid; g < groupsW; g += 256 * 512) {
        const float4* wp = (const float4*)(Wt + (size_t)g * 8);
        float4 w0 = wp[0], w1 = wp[1];
        v8s o;
        o[0] = (short)f2bf(w0.x); o[1] = (short)f2bf(w0.y);
        o[2] = (short)f2bf(w0.z); o[3] = (short)f2bf(w0.w);
        o[4] = (short)f2bf(w1.x); o[5] = (short)f2bf(w1.y);
        o[6] = (short)f2bf(w1.z); o[7] = (short)f2bf(w1.w);
        *(v8s*)(Wbf + (size_t)g * 8) = o;
    }

    __threadfence();                       // device-scope release of Abf/Wbf/mwz
    cooperative_groups::this_grid().sync();

    // ===================== Section 2: GEMM (R3 verbatim) =====================
    __shared__ __align__(16) unsigned short lA0[BM * BK];   // 32 KiB
    __shared__ __align__(16) unsigned short lA1[BM * BK];   // 32 KiB
    __shared__ __align__(16) unsigned short lB0[BN * BK];   // 32 KiB
    __shared__ __align__(16) unsigned short lB1[BN * BK];   // 32 KiB

    const int lane = tid & 63;
    const int wave = tid >> 6;        // 0..7
    const int wr   = wave & 1;        // M half (128 rows)
    const int wc   = wave >> 1;       // N quarter (64 cols)
    const int quad = lane >> 4;       // 0..3
    const int mcol = lane & 15;       // 0..15

    // R3-proven mapping: br fast in blockIdx.x, bc in blockIdx.y.
    const int br = blockIdx.x;        // 32 row-blocks
    const int bc = blockIdx.y;        // 8 col-blocks

    const unsigned short* gA = Abf + (size_t)(br * BM) * KDIM;
    const unsigned short* gB = Wbf + (size_t)(bc * BN) * KDIM;

    v4f acc[8][4];
    const v4f vzero = {0.f, 0.f, 0.f, 0.f};
    #pragma unroll
    for (int i = 0; i < 8; i++)
        #pragma unroll
        for (int j = 0; j < 4; j++) acc[i][j] = vzero;

    // --- stage one 64-row quarter (8 KiB = 512 thr x 16 B) of a tile ---
    // LDS slot f holds row=f>>3, global chunk ch=(f&7)^(row&7)  (verified T2)
    auto stage = [&](unsigned short* dst, const unsigned short* gsrc,
                     int t, int s) {
        const int f   = (s << 9) + tid;
        const int row = f >> 3;
        const int ch  = (f & 7) ^ (row & 7);
        const unsigned short* g = gsrc + (size_t)row * KDIM + ((t & 31) << 6) + (ch << 3);
        __builtin_amdgcn_global_load_lds(
            (const __attribute__((address_space(1))) void*)g,
            (__attribute__((address_space(3))) void*)(dst + ((size_t)f << 3)),
            16, 0, 0);
    };

    // --- fragment reads (identical unswizzle math to verified R3 kernel) ---
    auto rdA = [&](const unsigned short* l, int i, int ks) -> v8s {
        const int row = (wr << 7) + (i << 4) + mcol;
        const int c   = ((ks << 2) + quad) ^ (row & 7);
        return *(const v8s*)(l + (row << 6) + (c << 3));
    };
    auto rdB = [&](const unsigned short* l, int j, int ks) -> v8s {
        const int col = (wc << 6) + (j << 4) + mcol;
        const int c   = ((ks << 2) + quad) ^ (col & 7);
        return *(const v8s*)(l + (col << 6) + (c << 3));
    };

    // ---- prologue: tile0 fully + tile1 {B*, A-q0,A-q2}; 14 calls in flight
    stage(lB0, gB, 0, 0); stage(lB0, gB, 0, 1);
    stage(lB0, gB, 0, 2); stage(lB0, gB, 0, 3);
    stage(lA0, gA, 0, 0); stage(lA0, gA, 0, 2);
    stage(lA0, gA, 0, 1); stage(lA0, gA, 0, 3);
    stage(lB1, gB, 1, 0); stage(lB1, gB, 1, 1);
    stage(lB1, gB, 1, 2); stage(lB1, gB, 1, 3);
    stage(lA1, gA, 1, 0); stage(lA1, gA, 1, 2);
    VMCNT(8);                 // oldest 6 = [t0: B*, A-q0,A-q2] landed
    SBAR();

    #pragma unroll 1
    for (int tt = 0; tt < NT; tt += 2) {
        KTILE(lA0, lB0, lA1, tt);       // even tile: bufs 0
        KTILE(lA1, lB1, lA0, tt + 1);   // odd tile:  bufs 1
    }

    // ---- epilogue: bias + relu + scale + relu, dwordx4 fp32 stores ----
    // operand swap => acc holds out^T tile: reg-index = output COLUMN,
    // mcol = output ROW. Row parity = mcol & 1 (all tile offsets even).
    const float mz = mwz[mcol & 1];
    #pragma unroll
    for (int j = 0; j < 4; ++j) {
        const int ncol = bc * BN + wc * 64 + j * 16 + quad * 4;
        const float4 b4 = *(const float4*)(bt + ncol);
        #pragma unroll
        for (int i = 0; i < 8; ++i) {
            const int row = br * BM + wr * 128 + i * 16 + mcol;
            float4 o;
            o.x = fmaxf(mz * fmaxf(acc[i][j][0] + b4.x, 0.0f), 0.0f);
            o.y = fmaxf(mz * fmaxf(acc[i][j][1] + b4.y, 0.0f), 0.0f);
            o.z = fmaxf(mz * fmaxf(acc[i][j][2] + b4.z, 0.0f), 0.0f);
            o.w = fmaxf(mz * fmaxf(acc[i][j][3] + b4.w, 0.0f), 0.0f);
            *(float4*)(out + (size_t)row * NDIM + ncol) = o;
        }
    }
}

// ---------------------------------------------------------------------------
extern "C" void kernel_launch(void* const* d_in, const int* in_sizes, int n_in,
                              void* d_out, int out_size, void* d_ws, size_t ws_size,
                              hipStream_t stream) {
    const float* x    = (const float*)d_in[0];
    const int*   ids  = (const int*)  d_in[1];
    const float* mw   = (const float*)d_in[2];
    const float* emb  = (const float*)d_in[3];
    const float* Wt   = (const float*)d_in[4];
    const float* bt   = (const float*)d_in[5];
    const float* Wrc  = (const float*)d_in[6];
    const float* brc  = (const float*)d_in[7];
    float* out = (float*)d_out;

    char* ws = (char*)d_ws;
    unsigned short* Abf = (unsigned short*)(ws + A_OFF);
    unsigned short* Wbf = (unsigned short*)(ws + W_OFF);
    float* mwz          = (float*)(ws + MWZ_OFF);

    void* args[] = { (void*)&x, (void*)&ids, (void*)&mw, (void*)&emb,
                     (void*)&Wrc, (void*)&brc, (void*)&Wt, (void*)&bt,
                     (void*)&Abf, (void*)&Wbf, (void*)&mwz, (void*)&out };

    // 32 x 8 = 256 blocks = 1/CU exactly (co-resident: 130 KiB LDS, <=256 reg)
    hipLaunchCooperativeKernel((const void*)fused_kernel,
                               dim3(MROWS / BM, NDIM / BN), dim3(512),
                               args, 0, stream);
}

// Round 7
// 222.979 us; speedup vs baseline: 1.4691x; 1.4691x over previous
//
#include <hip/hip_runtime.h>
#include <hip/hip_bf16.h>
#include <math.h>

// Problem dims (fixed by the reference): B=4096, M=2, D=2048
#define MROWS 8192   // B*M rows of the GEMM
#define KDIM  2048
#define NDIM  2048

#define BM 128
#define BN 128
#define BK 32
#define NT (KDIM / BK)   // 64 K-tiles

typedef short  v8s __attribute__((ext_vector_type(8)));   // 8 bf16 (4 VGPRs)
typedef float  v4f __attribute__((ext_vector_type(4)));   // MFMA acc

// workspace layout (bytes)
#define A_OFF   0ull
#define W_OFF   ((unsigned long long)MROWS * KDIM * 2ull)               // 32 MiB
#define MWZ_OFF (W_OFF + (unsigned long long)NDIM * KDIM * 2ull)        // +8 MiB

__device__ inline unsigned short f2bf(float f) {
    __hip_bfloat16 h = __float2bfloat16(f);   // RNE
    return *reinterpret_cast<unsigned short*>(&h);
}

// ---------------------------------------------------------------------------
// Prep: zeta scalar, A = bf16(x + emb[ids]), W = bf16(Wt).
// Kept as a SEPARATE fat-grid kernel: R6 measured that this conversion is
// TLP-bound — inside the 256-block cooperative kernel it ran ~130 us vs ~8 us
// here (2048 blocks). Fusion is strictly wrong for this stage.
// ---------------------------------------------------------------------------
__global__ __launch_bounds__(256) void prep_kernel(
    const float* __restrict__ x, const int* __restrict__ ids,
    const float* __restrict__ mw, const float* __restrict__ emb,
    const float* __restrict__ Wrc, const float* __restrict__ brc,
    const float* __restrict__ Wt,
    unsigned short* __restrict__ Abf, unsigned short* __restrict__ Wbf,
    float* __restrict__ mwz)
{
    const int tid = threadIdx.x;

    if (blockIdx.x == 0) {
        __shared__ float red[256];
        float s = 0.f;
        for (int d = tid; d < KDIM; d += 256) s += Wrc[d];
        red[tid] = s;
        __syncthreads();
        for (int off = 128; off > 0; off >>= 1) {
            if (tid < off) red[tid] += red[tid + off];
            __syncthreads();
        }
        if (tid == 0) {
            float zeta = 1.0f / (1.0f + expf(-(0.2f * red[0] + brc[0])));
            mwz[0] = mw[0] * zeta;
            mwz[1] = mw[1] * zeta;
        }
    }

    const int groupsA = MROWS * KDIM / 8;
    for (int g = blockIdx.x * 256 + tid; g < groupsA; g += gridDim.x * 256) {
        const int row = g >> 8;
        const int off = (g & 255) << 3;
        const int st  = ids[row];
        const float4* xp = (const float4*)(x   + (size_t)row * KDIM + off);
        const float4* ep = (const float4*)(emb + (size_t)st  * KDIM + off);
        float4 x0 = xp[0], x1 = xp[1];
        float4 e0 = ep[0], e1 = ep[1];
        v8s o;
        o[0] = (short)f2bf(x0.x + e0.x);
        o[1] = (short)f2bf(x0.y + e0.y);
        o[2] = (short)f2bf(x0.z + e0.z);
        o[3] = (short)f2bf(x0.w + e0.w);
        o[4] = (short)f2bf(x1.x + e1.x);
        o[5] = (short)f2bf(x1.y + e1.y);
        o[6] = (short)f2bf(x1.z + e1.z);
        o[7] = (short)f2bf(x1.w + e1.w);
        *(v8s*)(Abf + (size_t)g * 8) = o;
    }

    const int groupsW = NDIM * KDIM / 8;
    for (int g = blockIdx.x * 256 + tid; g < groupsW; g += gridDim.x * 256) {
        const float4* wp = (const float4*)(Wt + (size_t)g * 8);
        float4 w0 = wp[0], w1 = wp[1];
        v8s o;
        o[0] = (short)f2bf(w0.x); o[1] = (short)f2bf(w0.y);
        o[2] = (short)f2bf(w0.z); o[3] = (short)f2bf(w0.w);
        o[4] = (short)f2bf(w1.x); o[5] = (short)f2bf(w1.y);
        o[6] = (short)f2bf(w1.z); o[7] = (short)f2bf(w1.w);
        *(v8s*)(Wbf + (size_t)g * 8) = o;
    }
}

// ---------------------------------------------------------------------------
// GEMM v7: OCCUPANCY/OVERLAP experiment — the one axis not yet varied.
// All four prior schedules (2-barrier, 8-phase counted, static-dbuf, 2-phase
// drain) measured 75-82 us / ~36% MfmaUtil at 2 waves/SIMD in ONE barrier
// domain per CU: every drain/barrier-skew is globally exposed, nothing
// backfills. This version: 128x128 tile, 4 waves (2Mx2N, wave = 64x64 out ->
// acc 4x4 frags = 64 VGPR), BK=32, static-dbuf LDS = 32 KiB/block,
// __launch_bounds__(256,4): 4 blocks/CU x 4 waves = 4 waves/SIMD in FOUR
// INDEPENDENT barrier domains (VGPR 4x128 = 512 exact, LDS 4x32 = 128 <= 160,
// grid 64x16 = 1024 = 4/CU exact). While one block sits in its vmcnt/barrier
// drain, three other blocks feed the MFMA pipe (m114 mechanism, m97's ~3
// blocks/CU geometry). Schedule = proven-simplest 2-phase per K-tile:
// {stage t+1 into other bufs -> ds_read+MFMA from current -> lgkm0+vmcnt0+
// barrier}.
//
// Verified components preserved under affine rescale:
//  - fetch-side XOR swizzle, re-derived for 64-B rows (4 chunks of 16 B):
//    ch = (f&3) ^ ((row>>1)&3). Bank check: 16-lane quad-group reads spread
//    over 8 slots x 4 banks with 2 accesses/bank = structural minimum, no
//    conflict (same quality as R3's measured-0 pattern).
//  - fragment k-mapping: per-lane v8s = k[quad*8 .. quad*8+7] (BK=32 -> one
//    ks step), identical element semantics to the verified R0-R3 path.
//  - operand swap mfma(b,a): acc[i][j] reg r = out column, mcol = out row.
//  - per-thread LDS/global offsets hoisted out of the loop (was 14% VALUBusy).
// ---------------------------------------------------------------------------

#define SBAR()   __builtin_amdgcn_s_barrier()
#define LGKM0()  asm volatile("s_waitcnt lgkmcnt(0)" ::: "memory")
#define VMCNT0() asm volatile("s_waitcnt vmcnt(0)" ::: "memory")

#define GLDS(gp, lp)                                                      \
    __builtin_amdgcn_global_load_lds(                                     \
        (const __attribute__((address_space(1))) void*)(gp),              \
        (__attribute__((address_space(3))) void*)(lp), 16, 0, 0)

__global__ __launch_bounds__(256, 4) void gemm_kernel(
    const unsigned short* __restrict__ Abf,
    const unsigned short* __restrict__ Wbf,
    const float* __restrict__ bt,
    const float* __restrict__ mwz,
    float* __restrict__ out)
{
    // STATIC double-buffers: four distinct LDS objects, 8 KiB each = 32 KiB.
    __shared__ __align__(16) unsigned short lA0[BM * BK];
    __shared__ __align__(16) unsigned short lA1[BM * BK];
    __shared__ __align__(16) unsigned short lB0[BN * BK];
    __shared__ __align__(16) unsigned short lB1[BN * BK];

    const int tid  = threadIdx.x;
    const int lane = tid & 63;
    const int wave = tid >> 6;        // 0..3
    const int wm   = wave & 1;        // M half (64 rows)
    const int wn   = wave >> 1;       // N half (64 cols)
    const int quad = lane >> 4;       // 0..3  (k-chunk of 8)
    const int mcol = lane & 15;       // 0..15

    const int br = blockIdx.x;        // 64 row-blocks (fast — proven mapping)
    const int bc = blockIdx.y;        // 16 col-blocks

    const unsigned short* gA = Abf + (size_t)(br * BM) * KDIM;
    const unsigned short* gB = Wbf + (size_t)(bc * BN) * KDIM;

    // ---- per-thread staging constants (A and B share 128x32 geometry) ----
    // call s covers f = s*256 + tid; row = f>>2; LDS chunk (f&3) holds global
    // chunk ch = (f&3) ^ ((row>>1)&3); LDS dest = f*16 B (linear, as required
    // by global_load_lds).
    const int f0 = tid,        r0 = f0 >> 2, c0 = (f0 & 3) ^ ((r0 >> 1) & 3);
    const int f1 = 256 + tid,  r1 = f1 >> 2, c1 = (f1 & 3) ^ ((r1 >> 1) & 3);
    const int gOff0 = r0 * KDIM + c0 * 8;     // short units, + t*32 per tile
    const int gOff1 = r1 * KDIM + c1 * 8;
    const int lOff0 = f0 * 8;                 // short units
    const int lOff1 = f1 * 8;

    // ---- per-thread fragment-read offsets (constant across tiles) ----
    int aOff[4], bOff[4];
    #pragma unroll
    for (int i = 0; i < 4; ++i) {
        const int r = wm * 64 + i * 16 + mcol;
        aOff[i] = r * BK + (quad ^ ((r >> 1) & 3)) * 8;
    }
    #pragma unroll
    for (int j = 0; j < 4; ++j) {
        const int c = wn * 64 + j * 16 + mcol;
        bOff[j] = c * BK + (quad ^ ((c >> 1) & 3)) * 8;
    }

    v4f acc[4][4];
    const v4f vzero = {0.f, 0.f, 0.f, 0.f};
    #pragma unroll
    for (int i = 0; i < 4; i++)
        #pragma unroll
        for (int j = 0; j < 4; j++) acc[i][j] = vzero;

#define STAGE(NA, NB, T)                                                  \
    do {                                                                  \
        const int kt = (T) << 5;                                          \
        GLDS(gA + gOff0 + kt, NA + lOff0);                                \
        GLDS(gA + gOff1 + kt, NA + lOff1);                                \
        GLDS(gB + gOff0 + kt, NB + lOff0);                                \
        GLDS(gB + gOff1 + kt, NB + lOff1);                                \
    } while (0)

#define COMPUTE(CA, CB)                                                   \
    do {                                                                  \
        v8s a0 = *(const v8s*)((CA) + aOff[0]);                           \
        v8s a1 = *(const v8s*)((CA) + aOff[1]);                           \
        v8s a2 = *(const v8s*)((CA) + aOff[2]);                           \
        v8s a3 = *(const v8s*)((CA) + aOff[3]);                           \
        v8s b0 = *(const v8s*)((CB) + bOff[0]);                           \
        v8s b1 = *(const v8s*)((CB) + bOff[1]);                           \
        v8s b2 = *(const v8s*)((CB) + bOff[2]);                           \
        v8s b3 = *(const v8s*)((CB) + bOff[3]);                           \
        __builtin_amdgcn_s_setprio(1);                                    \
        acc[0][0] = __builtin_amdgcn_mfma_f32_16x16x32_bf16(b0, a0, acc[0][0], 0, 0, 0); \
        acc[1][0] = __builtin_amdgcn_mfma_f32_16x16x32_bf16(b0, a1, acc[1][0], 0, 0, 0); \
        acc[2][0] = __builtin_amdgcn_mfma_f32_16x16x32_bf16(b0, a2, acc[2][0], 0, 0, 0); \
        acc[3][0] = __builtin_amdgcn_mfma_f32_16x16x32_bf16(b0, a3, acc[3][0], 0, 0, 0); \
        acc[0][1] = __builtin_amdgcn_mfma_f32_16x16x32_bf16(b1, a0, acc[0][1], 0, 0, 0); \
        acc[1][1] = __builtin_amdgcn_mfma_f32_16x16x32_bf16(b1, a1, acc[1][1], 0, 0, 0); \
        acc[2][1] = __builtin_amdgcn_mfma_f32_16x16x32_bf16(b1, a2, acc[2][1], 0, 0, 0); \
        acc[3][1] = __builtin_amdgcn_mfma_f32_16x16x32_bf16(b1, a3, acc[3][1], 0, 0, 0); \
        acc[0][2] = __builtin_amdgcn_mfma_f32_16x16x32_bf16(b2, a0, acc[0][2], 0, 0, 0); \
        acc[1][2] = __builtin_amdgcn_mfma_f32_16x16x32_bf16(b2, a1, acc[1][2], 0, 0, 0); \
        acc[2][2] = __builtin_amdgcn_mfma_f32_16x16x32_bf16(b2, a2, acc[2][2], 0, 0, 0); \
        acc[3][2] = __builtin_amdgcn_mfma_f32_16x16x32_bf16(b2, a3, acc[3][2], 0, 0, 0); \
        acc[0][3] = __builtin_amdgcn_mfma_f32_16x16x32_bf16(b3, a0, acc[0][3], 0, 0, 0); \
        acc[1][3] = __builtin_amdgcn_mfma_f32_16x16x32_bf16(b3, a1, acc[1][3], 0, 0, 0); \
        acc[2][3] = __builtin_amdgcn_mfma_f32_16x16x32_bf16(b3, a2, acc[2][3], 0, 0, 0); \
        acc[3][3] = __builtin_amdgcn_mfma_f32_16x16x32_bf16(b3, a3, acc[3][3], 0, 0, 0); \
        __builtin_amdgcn_s_setprio(0);                                    \
    } while (0)

// One K-tile: stage t+1 into other bufs, compute t from current, single
// drain+barrier. Cross-tile safety: stage targets bufs whose reads finished
// before the PREVIOUS tile's closing barrier (LGKM0 pinned); within-tile the
// DMA writes and ds_reads touch distinct static objects.
#define KT(CA, CB, NA, NB, T)                                             \
    {                                                                     \
        if ((T) + 1 < NT) STAGE(NA, NB, (T) + 1);                         \
        COMPUTE(CA, CB);                                                  \
        LGKM0(); VMCNT0(); SBAR();                                        \
    }

    // ---- prologue: stage tile 0, drain, sync ----
    STAGE(lA0, lB0, 0);
    VMCNT0();
    SBAR();

    #pragma unroll 1
    for (int tt = 0; tt < NT; tt += 2) {
        KT(lA0, lB0, lA1, lB1, tt);       // even tile: bufs 0
        KT(lA1, lB1, lA0, lB0, tt + 1);   // odd tile:  bufs 1
    }

    // ---- epilogue: bias + relu + scale + relu, dwordx4 fp32 stores ----
    // operand swap => acc holds out^T tile: reg r = output COLUMN, mcol =
    // output ROW. Row parity = mcol & 1 (all tile offsets even).
    const float mz = mwz[mcol & 1];
    #pragma unroll
    for (int j = 0; j < 4; ++j) {
        const int ncol = bc * BN + wn * 64 + j * 16 + quad * 4;
        const float4 b4 = *(const float4*)(bt + ncol);
        #pragma unroll
        for (int i = 0; i < 4; ++i) {
            const int row = br * BM + wm * 64 + i * 16 + mcol;
            float4 o;
            o.x = fmaxf(mz * fmaxf(acc[i][j][0] + b4.x, 0.0f), 0.0f);
            o.y = fmaxf(mz * fmaxf(acc[i][j][1] + b4.y, 0.0f), 0.0f);
            o.z = fmaxf(mz * fmaxf(acc[i][j][2] + b4.z, 0.0f), 0.0f);
            o.w = fmaxf(mz * fmaxf(acc[i][j][3] + b4.w, 0.0f), 0.0f);
            *(float4*)(out + (size_t)row * NDIM + ncol) = o;
        }
    }

#undef KT
#undef COMPUTE
#undef STAGE
}

// ---------------------------------------------------------------------------
extern "C" void kernel_launch(void* const* d_in, const int* in_sizes, int n_in,
                              void* d_out, int out_size, void* d_ws, size_t ws_size,
                              hipStream_t stream) {
    const float* x    = (const float*)d_in[0];
    const int*   ids  = (const int*)  d_in[1];
    const float* mw   = (const float*)d_in[2];
    const float* emb  = (const float*)d_in[3];
    const float* Wt   = (const float*)d_in[4];
    const float* bt   = (const float*)d_in[5];
    const float* Wrc  = (const float*)d_in[6];
    const float* brc  = (const float*)d_in[7];
    float* out = (float*)d_out;

    char* ws = (char*)d_ws;
    unsigned short* Abf = (unsigned short*)(ws + A_OFF);
    unsigned short* Wbf = (unsigned short*)(ws + W_OFF);
    float* mwz          = (float*)(ws + MWZ_OFF);

    prep_kernel<<<2048, 256, 0, stream>>>(x, ids, mw, emb, Wrc, brc, Wt,
                                          Abf, Wbf, mwz);

    dim3 grid(MROWS / BM, NDIM / BN);   // 64 x 16 = 1024 blocks = 4/CU exactly
    gemm_kernel<<<grid, 256, 0, stream>>>(Abf, Wbf, bt, mwz, out);
}

// Round 8
// 199.088 us; speedup vs baseline: 1.6454x; 1.1200x over previous
//
#include <hip/hip_runtime.h>
#include <hip/hip_bf16.h>
#include <math.h>

// Problem dims (fixed by the reference): B=4096, M=2, D=2048
#define MROWS 8192   // B*M rows of the GEMM
#define KDIM  2048
#define NDIM  2048

#define BM 256
#define BN 256
#define BK 64
#define NT (KDIM / BK)   // 32 K-tiles

typedef short  v8s __attribute__((ext_vector_type(8)));   // 8 bf16 (4 VGPRs)
typedef float  v4f __attribute__((ext_vector_type(4)));   // MFMA acc

// workspace layout (bytes)
#define A_OFF   0ull
#define W_OFF   ((unsigned long long)MROWS * KDIM * 2ull)               // 32 MiB
#define MWZ_OFF (W_OFF + (unsigned long long)NDIM * KDIM * 2ull)        // +8 MiB

__device__ inline unsigned short f2bf(float f) {
    __hip_bfloat16 h = __float2bfloat16(f);   // RNE
    return *reinterpret_cast<unsigned short*>(&h);
}

// ---------------------------------------------------------------------------
// Prep: zeta scalar, A = bf16(x + emb[ids]), W = bf16(Wt)   [UNCHANGED —
// R6 measured this stage is TLP-bound: ~8-20 us at 2048 blocks vs ~130 us
// inside a 256-block cooperative kernel. It stays a separate fat-grid launch.]
// ---------------------------------------------------------------------------
__global__ __launch_bounds__(256) void prep_kernel(
    const float* __restrict__ x, const int* __restrict__ ids,
    const float* __restrict__ mw, const float* __restrict__ emb,
    const float* __restrict__ Wrc, const float* __restrict__ brc,
    const float* __restrict__ Wt,
    unsigned short* __restrict__ Abf, unsigned short* __restrict__ Wbf,
    float* __restrict__ mwz)
{
    const int tid = threadIdx.x;

    if (blockIdx.x == 0) {
        __shared__ float red[256];
        float s = 0.f;
        for (int d = tid; d < KDIM; d += 256) s += Wrc[d];
        red[tid] = s;
        __syncthreads();
        for (int off = 128; off > 0; off >>= 1) {
            if (tid < off) red[tid] += red[tid + off];
            __syncthreads();
        }
        if (tid == 0) {
            float zeta = 1.0f / (1.0f + expf(-(0.2f * red[0] + brc[0])));
            mwz[0] = mw[0] * zeta;
            mwz[1] = mw[1] * zeta;
        }
    }

    const int groupsA = MROWS * KDIM / 8;
    for (int g = blockIdx.x * 256 + tid; g < groupsA; g += gridDim.x * 256) {
        const int row = g >> 8;
        const int off = (g & 255) << 3;
        const int st  = ids[row];
        const float4* xp = (const float4*)(x   + (size_t)row * KDIM + off);
        const float4* ep = (const float4*)(emb + (size_t)st  * KDIM + off);
        float4 x0 = xp[0], x1 = xp[1];
        float4 e0 = ep[0], e1 = ep[1];
        v8s o;
        o[0] = (short)f2bf(x0.x + e0.x);
        o[1] = (short)f2bf(x0.y + e0.y);
        o[2] = (short)f2bf(x0.z + e0.z);
        o[3] = (short)f2bf(x0.w + e0.w);
        o[4] = (short)f2bf(x1.x + e1.x);
        o[5] = (short)f2bf(x1.y + e1.y);
        o[6] = (short)f2bf(x1.z + e1.z);
        o[7] = (short)f2bf(x1.w + e1.w);
        *(v8s*)(Abf + (size_t)g * 8) = o;
    }

    const int groupsW = NDIM * KDIM / 8;
    for (int g = blockIdx.x * 256 + tid; g < groupsW; g += gridDim.x * 256) {
        const float4* wp = (const float4*)(Wt + (size_t)g * 8);
        float4 w0 = wp[0], w1 = wp[1];
        v8s o;
        o[0] = (short)f2bf(w0.x); o[1] = (short)f2bf(w0.y);
        o[2] = (short)f2bf(w0.z); o[3] = (short)f2bf(w0.w);
        o[4] = (short)f2bf(w1.x); o[5] = (short)f2bf(w1.y);
        o[6] = (short)f2bf(w1.z); o[7] = (short)f2bf(w1.w);
        *(v8s*)(Wbf + (size_t)g * 8) = o;
    }
}

// ---------------------------------------------------------------------------
// GEMM v8 = v4/R3 (session-best: 75.7 us, MfmaUtil 36.5, bank conflicts 0,
// FETCH compulsory-only) with ONE change: s_setprio REMOVED. T5 isolation
// data (m190) shows setprio is null-to-negative (-1.5%) on lockstep
// single-domain GEMM structures — its gain requires per-phase wave role
// diversity, which this barrier-locked schedule doesn't have.
//
// Session record (all counter-verified): five structural axes — barrier
// count (8/4/2/1 per K-tile), wait discipline (counted vs drain), LDS buffer
// aliasing (runtime vs static), B-operand path (LDS vs L2-direct regs),
// block/CU topology (1/2/4 independent barrier domains) — all converge on
// 75-95 us / 30-37% MfmaUtil. This structure is the measured optimum.
//
// Structure: 256x256 tile, 8 waves (2Mx4N), BK=64, static LDS double-buffers
// (four distinct objects so SIInsertWaitcnts can prove DMA/ds_read
// non-aliasing), 4-phase/K-tile with counted cross-barrier vmcnt, fetch-side
// XOR swizzle, 2D block mapping (br fast), operand-swap epilogue.
// ---------------------------------------------------------------------------

#define SBAR()   __builtin_amdgcn_s_barrier()
#define LGKM0()  asm volatile("s_waitcnt lgkmcnt(0)" ::: "memory")
#define VMCNT(n) asm volatile("s_waitcnt vmcnt(" #n ")" ::: "memory")

template<int P>
__device__ __forceinline__ void mfma_phase(v4f (&acc)[8][4],
                                           const v8s (&b)[4][2],
                                           const v8s (&a)[2][2])
{
    #pragma unroll
    for (int j = 0; j < 4; ++j) {
        acc[2*P  ][j] = __builtin_amdgcn_mfma_f32_16x16x32_bf16(b[j][0], a[0][0], acc[2*P  ][j], 0, 0, 0);
        acc[2*P+1][j] = __builtin_amdgcn_mfma_f32_16x16x32_bf16(b[j][0], a[1][0], acc[2*P+1][j], 0, 0, 0);
    }
    #pragma unroll
    for (int j = 0; j < 4; ++j) {
        acc[2*P  ][j] = __builtin_amdgcn_mfma_f32_16x16x32_bf16(b[j][1], a[0][1], acc[2*P  ][j], 0, 0, 0);
        acc[2*P+1][j] = __builtin_amdgcn_mfma_f32_16x16x32_bf16(b[j][1], a[1][1], acc[2*P+1][j], 0, 0, 0);
    }
}

// One K-tile = 4 phases. CA/CB: buffers computed from (and stage target for
// t+2, same parity). OA: other A buffer (stage target for t+1).
#define KTILE(CA, CB, OA, T)                                              \
  {                                                                       \
    v8s a[2][2], b[4][2];                                                 \
    b[0][0] = rdB(CB, 0, 0); b[0][1] = rdB(CB, 0, 1);                     \
    b[1][0] = rdB(CB, 1, 0); b[1][1] = rdB(CB, 1, 1);                     \
    b[2][0] = rdB(CB, 2, 0); b[2][1] = rdB(CB, 2, 1);                     \
    b[3][0] = rdB(CB, 3, 0); b[3][1] = rdB(CB, 3, 1);                     \
    a[0][0] = rdA(CA, 0, 0); a[0][1] = rdA(CA, 0, 1);                     \
    a[1][0] = rdA(CA, 1, 0); a[1][1] = rdA(CA, 1, 1);                     \
    stage(OA, gA, (T) + 1, 1); stage(OA, gA, (T) + 1, 3);                 \
    SBAR(); mfma_phase<0>(acc, b, a); LGKM0(); SBAR();                    \
    a[0][0] = rdA(CA, 2, 0); a[0][1] = rdA(CA, 2, 1);                     \
    a[1][0] = rdA(CA, 3, 0); a[1][1] = rdA(CA, 3, 1);                     \
    stage(CB, gB, (T) + 2, 0); stage(CB, gB, (T) + 2, 1);                 \
    SBAR(); mfma_phase<1>(acc, b, a); LGKM0(); VMCNT(10); SBAR();         \
    a[0][0] = rdA(CA, 4, 0); a[0][1] = rdA(CA, 4, 1);                     \
    a[1][0] = rdA(CA, 5, 0); a[1][1] = rdA(CA, 5, 1);                     \
    stage(CB, gB, (T) + 2, 2); stage(CB, gB, (T) + 2, 3);                 \
    SBAR(); mfma_phase<2>(acc, b, a); LGKM0(); SBAR();                    \
    a[0][0] = rdA(CA, 6, 0); a[0][1] = rdA(CA, 6, 1);                     \
    a[1][0] = rdA(CA, 7, 0); a[1][1] = rdA(CA, 7, 1);                     \
    stage(CA, gA, (T) + 2, 0); stage(CA, gA, (T) + 2, 2);                 \
    SBAR(); mfma_phase<3>(acc, b, a); LGKM0(); VMCNT(8); SBAR();          \
  }

__global__ __launch_bounds__(512, 2) void gemm_kernel(
    const unsigned short* __restrict__ Abf,
    const unsigned short* __restrict__ Wbf,
    const float* __restrict__ bt,
    const float* __restrict__ mwz,
    float* __restrict__ out)
{
    // STATIC double-buffers: four distinct LDS objects.
    __shared__ __align__(16) unsigned short lA0[BM * BK];   // 32 KiB
    __shared__ __align__(16) unsigned short lA1[BM * BK];   // 32 KiB
    __shared__ __align__(16) unsigned short lB0[BN * BK];   // 32 KiB
    __shared__ __align__(16) unsigned short lB1[BN * BK];   // 32 KiB

    const int tid  = threadIdx.x;
    const int lane = tid & 63;
    const int wave = tid >> 6;        // 0..7
    const int wr   = wave & 1;        // M half (128 rows)
    const int wc   = wave >> 1;       // N quarter (64 cols)
    const int quad = lane >> 4;       // 0..3
    const int mcol = lane & 15;       // 0..15

    // R3-proven mapping: br fast in blockIdx.x, bc in blockIdx.y.
    const int br = blockIdx.x;        // 32 row-blocks
    const int bc = blockIdx.y;        // 8 col-blocks

    const unsigned short* gA = Abf + (size_t)(br * BM) * KDIM;
    const unsigned short* gB = Wbf + (size_t)(bc * BN) * KDIM;

    v4f acc[8][4];
    const v4f vzero = {0.f, 0.f, 0.f, 0.f};
    #pragma unroll
    for (int i = 0; i < 8; i++)
        #pragma unroll
        for (int j = 0; j < 4; j++) acc[i][j] = vzero;

    // --- stage one 64-row quarter (8 KiB = 512 thr x 16 B) of a tile ---
    // LDS slot f holds row=f>>3, global chunk ch=(f&7)^(row&7)  (verified T2)
    auto stage = [&](unsigned short* dst, const unsigned short* gsrc,
                     int t, int s) {
        const int f   = (s << 9) + tid;
        const int row = f >> 3;
        const int ch  = (f & 7) ^ (row & 7);
        const unsigned short* g = gsrc + (size_t)row * KDIM + ((t & 31) << 6) + (ch << 3);
        __builtin_amdgcn_global_load_lds(
            (const __attribute__((address_space(1))) void*)g,
            (__attribute__((address_space(3))) void*)(dst + ((size_t)f << 3)),
            16, 0, 0);
    };

    // --- fragment reads (identical unswizzle math to verified R3 kernel) ---
    auto rdA = [&](const unsigned short* l, int i, int ks) -> v8s {
        const int row = (wr << 7) + (i << 4) + mcol;
        const int c   = ((ks << 2) + quad) ^ (row & 7);
        return *(const v8s*)(l + (row << 6) + (c << 3));
    };
    auto rdB = [&](const unsigned short* l, int j, int ks) -> v8s {
        const int col = (wc << 6) + (j << 4) + mcol;
        const int c   = ((ks << 2) + quad) ^ (col & 7);
        return *(const v8s*)(l + (col << 6) + (c << 3));
    };

    // ---- prologue: tile0 fully + tile1 {B*, A-q0,A-q2}; 14 calls in flight
    stage(lB0, gB, 0, 0); stage(lB0, gB, 0, 1);
    stage(lB0, gB, 0, 2); stage(lB0, gB, 0, 3);
    stage(lA0, gA, 0, 0); stage(lA0, gA, 0, 2);
    stage(lA0, gA, 0, 1); stage(lA0, gA, 0, 3);
    stage(lB1, gB, 1, 0); stage(lB1, gB, 1, 1);
    stage(lB1, gB, 1, 2); stage(lB1, gB, 1, 3);
    stage(lA1, gA, 1, 0); stage(lA1, gA, 1, 2);
    VMCNT(8);                 // oldest 6 = [t0: B*, A-q0,A-q2] landed
    SBAR();

    #pragma unroll 1
    for (int tt = 0; tt < NT; tt += 2) {
        KTILE(lA0, lB0, lA1, tt);       // even tile: bufs 0
        KTILE(lA1, lB1, lA0, tt + 1);   // odd tile:  bufs 1
    }

    // ---- epilogue: bias + relu + scale + relu, dwordx4 fp32 stores ----
    // operand swap => acc holds out^T tile: reg-index = output COLUMN,
    // mcol = output ROW. Row parity = mcol & 1 (all tile offsets even).
    const float mz = mwz[mcol & 1];
    #pragma unroll
    for (int j = 0; j < 4; ++j) {
        const int ncol = bc * BN + wc * 64 + j * 16 + quad * 4;
        const float4 b4 = *(const float4*)(bt + ncol);
        #pragma unroll
        for (int i = 0; i < 8; ++i) {
            const int row = br * BM + wr * 128 + i * 16 + mcol;
            float4 o;
            o.x = fmaxf(mz * fmaxf(acc[i][j][0] + b4.x, 0.0f), 0.0f);
            o.y = fmaxf(mz * fmaxf(acc[i][j][1] + b4.y, 0.0f), 0.0f);
            o.z = fmaxf(mz * fmaxf(acc[i][j][2] + b4.z, 0.0f), 0.0f);
            o.w = fmaxf(mz * fmaxf(acc[i][j][3] + b4.w, 0.0f), 0.0f);
            *(float4*)(out + (size_t)row * NDIM + ncol) = o;
        }
    }
}

// ---------------------------------------------------------------------------
extern "C" void kernel_launch(void* const* d_in, const int* in_sizes, int n_in,
                              void* d_out, int out_size, void* d_ws, size_t ws_size,
                              hipStream_t stream) {
    const float* x    = (const float*)d_in[0];
    const int*   ids  = (const int*)  d_in[1];
    const float* mw   = (const float*)d_in[2];
    const float* emb  = (const float*)d_in[3];
    const float* Wt   = (const float*)d_in[4];
    const float* bt   = (const float*)d_in[5];
    const float* Wrc  = (const float*)d_in[6];
    const float* brc  = (const float*)d_in[7];
    float* out = (float*)d_out;

    char* ws = (char*)d_ws;
    unsigned short* Abf = (unsigned short*)(ws + A_OFF);
    unsigned short* Wbf = (unsigned short*)(ws + W_OFF);
    float* mwz          = (float*)(ws + MWZ_OFF);

    prep_kernel<<<2048, 256, 0, stream>>>(x, ids, mw, emb, Wrc, brc, Wt,
                                          Abf, Wbf, mwz);

    dim3 grid(MROWS / BM, NDIM / BN);   // 32 x 8 = 256 blocks = 1/CU exactly
    gemm_kernel<<<grid, 512, 0, stream>>>(Abf, Wbf, bt, mwz, out);
}